// Round 1
// baseline (1689.719 us; speedup 1.0000x reference)
//
#include <hip/hip_runtime.h>
#include <hip/hip_bf16.h>
#include <math.h>

#define NFEAT 128
#define NNODE 256
#define NHEAD 8
#define DHEAD 16
#define NLAYER 9

// ---------------------------------------------------------------------------
// adjacency build: adj[b][s][t] = 1 for each edge, deg[row] += 1
__global__ void build_adj_kernel(const int* __restrict__ ei, float* __restrict__ adj,
                                 float* __restrict__ deg, int E) {
  int e = blockIdx.x * 256 + threadIdx.x;
  if (e >= E) return;
  int r = ei[e], c = ei[E + e];
  int b = r >> 8;
  adj[((size_t)b << 16) + ((size_t)(r & 255) << 8) + (c & 255)] = 1.0f;
  atomicAdd(&deg[r], 1.0f);
}

// self loops on valid nodes; deg += 1; dis = deg^-1/2
__global__ void selfloop_deg_kernel(const int* __restrict__ nc, float* __restrict__ adj,
                                    float* __restrict__ deg, float* __restrict__ dis) {
  int n = blockIdx.x * 256 + threadIdx.x;
  int b = n >> 8, i = n & 255;
  if (i < nc[b]) adj[((size_t)b << 16) + ((size_t)i << 8) + i] = 1.0f;
  float d = deg[n] + 1.0f;
  deg[n] = d;
  dis[n] = rsqrtf(d);
}

// row-normalize (optionally r^6 inflation first): one block (256 thr) per row
__global__ __launch_bounds__(256) void norm_rows_kernel(const float* __restrict__ src,
                                                        float* __restrict__ dst, int inflate) {
  int row = blockIdx.x;
  int t = threadIdx.x;
  float v = src[(size_t)row * 256 + t];
  if (inflate) { float v2 = v * v; v = v2 * v2 * v2; }
  float s = v;
#pragma unroll
  for (int o = 32; o > 0; o >>= 1) s += __shfl_xor(s, o, 64);
  __shared__ float ws4[4];
  if ((t & 63) == 0) ws4[t >> 6] = s;
  __syncthreads();
  float tot = ws4[0] + ws4[1] + ws4[2] + ws4[3];
  dst[(size_t)row * 256 + t] = v / (tot + 1e-6f);
}

// batched 256x256x256 NN matmul: C[b] = M[b] @ R[b]; grid (4,4,B), 64x64 tile
__global__ __launch_bounds__(256) void mcl_mm_kernel(const float* __restrict__ Mg,
                                                     const float* __restrict__ Rg,
                                                     float* __restrict__ Cg) {
  int b = blockIdx.z;
  const float* M = Mg + ((size_t)b << 16);
  const float* R = Rg + ((size_t)b << 16);
  float* C = Cg + ((size_t)b << 16);
  int i0 = blockIdx.x * 64, j0 = blockIdx.y * 64;
  int t = threadIdx.x;
  __shared__ float Ms[16][64], Rs[16][64];
  int lr = t >> 2, lc = (t & 3) * 4;   // M loader
  int rr = t >> 4, rc = (t & 15) * 4;  // R loader
  int ti = t >> 4, tj = t & 15;
  float acc[4][4] = {};
  for (int kc = 0; kc < 256; kc += 16) {
    float4 a4 = *(const float4*)(M + (size_t)(i0 + lr) * 256 + kc + lc);
    float4 r4 = *(const float4*)(R + (size_t)(kc + rr) * 256 + j0 + rc);
    Ms[lc + 0][lr] = a4.x; Ms[lc + 1][lr] = a4.y; Ms[lc + 2][lr] = a4.z; Ms[lc + 3][lr] = a4.w;
    *(float4*)&Rs[rr][rc] = r4;
    __syncthreads();
#pragma unroll
    for (int kk = 0; kk < 16; kk++) {
      float av[4], bv[4];
#pragma unroll
      for (int i = 0; i < 4; i++) { av[i] = Ms[kk][ti * 4 + i]; bv[i] = Rs[kk][tj * 4 + i]; }
#pragma unroll
      for (int i = 0; i < 4; i++)
#pragma unroll
        for (int j = 0; j < 4; j++) acc[i][j] += av[i] * bv[j];
    }
    __syncthreads();
  }
#pragma unroll
  for (int i = 0; i < 4; i++)
#pragma unroll
    for (int j = 0; j < 4; j++)
      C[(size_t)(i0 + ti * 4 + i) * 256 + j0 + tj * 4 + j] = acc[i][j];
}

__device__ inline float gelu_exact(float x) {
  return 0.5f * x * (1.0f + erff(x * 0.7071067811865476f));
}

// C[M,O] = act(A[M,K] @ W[O,K]^T); ACT 0: *scale, 1: +bias, 2: gelu(x+bias)
template <int ACT>
__global__ __launch_bounds__(256) void gemm_nt_kernel(const float* __restrict__ A,
                                                      const float* __restrict__ W,
                                                      const float* __restrict__ bias,
                                                      float* __restrict__ C, int K, int O,
                                                      float scale) {
  int m0 = blockIdx.x * 64, o0 = blockIdx.y * 64;
  int t = threadIdx.x;
  __shared__ float As[16][64], Ws[16][64];
  int lr = t >> 2, lc = (t & 3) * 4;
  int tm = t >> 4, to = t & 15;
  float acc[4][4] = {};
  for (int kc = 0; kc < K; kc += 16) {
    float4 a4 = *(const float4*)(A + (size_t)(m0 + lr) * K + kc + lc);
    float4 w4 = *(const float4*)(W + (size_t)(o0 + lr) * K + kc + lc);
    As[lc + 0][lr] = a4.x; As[lc + 1][lr] = a4.y; As[lc + 2][lr] = a4.z; As[lc + 3][lr] = a4.w;
    Ws[lc + 0][lr] = w4.x; Ws[lc + 1][lr] = w4.y; Ws[lc + 2][lr] = w4.z; Ws[lc + 3][lr] = w4.w;
    __syncthreads();
#pragma unroll
    for (int kk = 0; kk < 16; kk++) {
      float av[4], bv[4];
#pragma unroll
      for (int i = 0; i < 4; i++) { av[i] = As[kk][tm * 4 + i]; bv[i] = Ws[kk][to * 4 + i]; }
#pragma unroll
      for (int i = 0; i < 4; i++)
#pragma unroll
        for (int j = 0; j < 4; j++) acc[i][j] += av[i] * bv[j];
    }
    __syncthreads();
  }
#pragma unroll
  for (int i = 0; i < 4; i++) {
    int m = m0 + tm * 4 + i;
#pragma unroll
    for (int j = 0; j < 4; j++) {
      int oo = o0 + to * 4 + j;
      float v = acc[i][j];
      if (ACT == 0) v *= scale;
      else if (ACT == 1) v += bias[oo];
      else if (ACT == 2) v = gelu_exact(v + bias[oo]);
      C[(size_t)m * O + oo] = v;
    }
  }
}

// fused edge message: msg = dis[r]*dis[c]*relu(h[r][f] + edge_attr[e]·We[f]); atomic scatter
__global__ void edge_msg_kernel(const int* __restrict__ ei, const float* __restrict__ ea,
                                const float* __restrict__ We, const float* __restrict__ h,
                                const float* __restrict__ dis, float* __restrict__ agg, int E) {
  int tid = blockIdx.x * 256 + threadIdx.x;
  if (tid >= E * 128) return;
  int e = tid >> 7, f = tid & 127;
  int r = ei[e], c = ei[E + e];
  const float* eae = ea + (size_t)e * 7;
  const float* wf = We + f * 7;
  float s = 0.f;
#pragma unroll
  for (int k = 0; k < 7; k++) s += eae[k] * wf[k];
  float msg = dis[r] * dis[c] * fmaxf(h[(size_t)r * 128 + f] + s, 0.f);
  atomicAdd(&agg[(size_t)c * 128 + f], msg);
}

// g = agg + relu(h + root_emb)/deg; out = relu(LN(g)) + out   (in-place residual)
__global__ __launch_bounds__(256) void gcn_post_kernel(const float* __restrict__ agg,
                                                       const float* __restrict__ h,
                                                       const float* __restrict__ remb,
                                                       const int* __restrict__ root,
                                                       const float* __restrict__ deg,
                                                       const float* __restrict__ gamma,
                                                       const float* __restrict__ beta,
                                                       float* __restrict__ out) {
  int n = blockIdx.x * 4 + (threadIdx.x >> 6);
  int lane = threadIdx.x & 63;
  int f0 = lane, f1 = lane + 64;
  float invd = 1.0f / deg[n];
  const float* re = remb + root[n] * 128;
  size_t base = (size_t)n * 128;
  float g0 = agg[base + f0] + fmaxf(h[base + f0] + re[f0], 0.f) * invd;
  float g1 = agg[base + f1] + fmaxf(h[base + f1] + re[f1], 0.f) * invd;
  float s = g0 + g1, ss = g0 * g0 + g1 * g1;
#pragma unroll
  for (int o = 32; o > 0; o >>= 1) { s += __shfl_xor(s, o, 64); ss += __shfl_xor(ss, o, 64); }
  float mu = s * 0.0078125f;
  float var = ss * 0.0078125f - mu * mu;
  float rs = rsqrtf(var + 1e-5f);
  float y0 = fmaxf((g0 - mu) * rs * gamma[f0] + beta[f0], 0.f);
  float y1 = fmaxf((g1 - mu) * rs * gamma[f1] + beta[f1], 0.f);
  out[base + f0] = y0 + out[base + f0];
  out[base + f1] = y1 + out[base + f1];
}

// dst = LN(a (+ res)) * gamma + beta
__global__ __launch_bounds__(256) void ln_add_kernel(const float* __restrict__ a,
                                                     const float* __restrict__ res,
                                                     const float* __restrict__ gamma,
                                                     const float* __restrict__ beta,
                                                     float* __restrict__ dst) {
  int n = blockIdx.x * 4 + (threadIdx.x >> 6);
  int lane = threadIdx.x & 63;
  size_t base = (size_t)n * 128;
  int f0 = lane, f1 = lane + 64;
  float x0 = a[base + f0], x1 = a[base + f1];
  if (res) { x0 += res[base + f0]; x1 += res[base + f1]; }
  float s = x0 + x1, ss = x0 * x0 + x1 * x1;
#pragma unroll
  for (int o = 32; o > 0; o >>= 1) { s += __shfl_xor(s, o, 64); ss += __shfl_xor(ss, o, 64); }
  float mu = s * 0.0078125f;
  float var = ss * 0.0078125f - mu * mu;
  float rs = rsqrtf(var + 1e-5f);
  dst[base + f0] = (x0 - mu) * rs * gamma[f0] + beta[f0];
  dst[base + f1] = (x1 - mu) * rs * gamma[f1] + beta[f1];
}

// biased MHA: grid (qtile=4, H, B), block 64; K/V head slice in LDS; online softmax
__global__ __launch_bounds__(64) void attn_kernel(const float* __restrict__ q,
                                                  const float* __restrict__ k,
                                                  const float* __restrict__ v,
                                                  const float* __restrict__ mcl,
                                                  const float* __restrict__ mclw,
                                                  const int* __restrict__ ncnt,
                                                  float* __restrict__ o) {
  int qt = blockIdx.x, hh = blockIdx.y, b = blockIdx.z;
  int t = threadIdx.x;
  __shared__ float ks[256][16];
  __shared__ float vs[256][16];
  for (int rr = 0; rr < 4; rr++) {
    int r = t + rr * 64;
    const float* kp = k + ((size_t)(b * 256 + r) * 128 + hh * 16);
    const float* vp = v + ((size_t)(b * 256 + r) * 128 + hh * 16);
#pragma unroll
    for (int d4 = 0; d4 < 16; d4 += 4) {
      *(float4*)&ks[r][d4] = *(const float4*)(kp + d4);
      *(float4*)&vs[r][d4] = *(const float4*)(vp + d4);
    }
  }
  __syncthreads();
  int i = qt * 64 + t;
  int nc = ncnt[b];
  float wh = mclw[hh];
  float qi[16];
  const float* qp = q + ((size_t)(b * 256 + i) * 128 + hh * 16);
#pragma unroll
  for (int d = 0; d < 16; d++) qi[d] = qp[d];
  bool vi = i < nc;
  const float* mrow = mcl + ((size_t)(b * 256 + i)) * 256;
  float mrun = -1e30f, lrun = 0.f;
  float acc[16];
#pragma unroll
  for (int d = 0; d < 16; d++) acc[d] = 0.f;
  for (int j0 = 0; j0 < 256; j0 += 4) {
    float4 mc = *(const float4*)(mrow + j0);
    float mcv[4] = {mc.x, mc.y, mc.z, mc.w};
#pragma unroll
    for (int jj = 0; jj < 4; jj++) {
      int j = j0 + jj;
      float sc = 0.f;
#pragma unroll
      for (int d = 0; d < 16; d++) sc += qi[d] * ks[j][d];
      sc += ((vi && (j < nc)) ? 0.f : -1024.f) + mcv[jj] * wh;
      float mn = fmaxf(mrun, sc);
      float corr = __expf(mrun - mn);
      float p = __expf(sc - mn);
      lrun = lrun * corr + p;
#pragma unroll
      for (int d = 0; d < 16; d++) acc[d] = acc[d] * corr + p * vs[j][d];
      mrun = mn;
    }
  }
  float inv = 1.f / lrun;
  float* op = o + ((size_t)(b * 256 + i) * 128 + hh * 16);
#pragma unroll
  for (int d = 0; d < 16; d++) op[d] = acc[d] * inv;
}

// ---------------------------------------------------------------------------
extern "C" void kernel_launch(void* const* d_in, const int* in_sizes, int n_in,
                              void* d_out, int out_size, void* d_ws, size_t ws_size,
                              hipStream_t stream) {
  const float* input_x = (const float*)d_in[0];
  const float* edge_attr = (const float*)d_in[1];
  const float* gcn_lin_w = (const float*)d_in[2];
  const float* gcn_root = (const float*)d_in[3];
  const float* gcn_edge_w = (const float*)d_in[4];
  const float* gcn_ng = (const float*)d_in[5];
  const float* gcn_nb = (const float*)d_in[6];
  const float* ln_in_g = (const float*)d_in[7];
  const float* ln_in_b = (const float*)d_in[8];
  const float* ln_ffn_g = (const float*)d_in[9];
  const float* ln_ffn_b = (const float*)d_in[10];
  const float* mcl_w = (const float*)d_in[11];
  const float* q_w = (const float*)d_in[12];
  const float* k_w = (const float*)d_in[13];
  const float* v_w = (const float*)d_in[14];
  const float* merge_w = (const float*)d_in[15];
  const float* merge_b = (const float*)d_in[16];
  const float* ffn_w1 = (const float*)d_in[17];
  const float* ffn_b1 = (const float*)d_in[18];
  const float* ffn_w2 = (const float*)d_in[19];
  const float* ffn_b2 = (const float*)d_in[20];
  const float* final_g = (const float*)d_in[21];
  const float* final_b = (const float*)d_in[22];
  const int* edge_index = (const int*)d_in[23];
  const int* n_counts = (const int*)d_in[24];
  const int* root = (const int*)d_in[25];

  const int E = in_sizes[23] / 2;
  const int B = in_sizes[24];
  const int BN = B * NNODE;

  float* ws = (float*)d_ws;
  size_t off = 0;
  auto alloc = [&](size_t n) { float* p = ws + off; off += n; return p; };
  const size_t NN2 = (size_t)B * 256 * 256;
  float* mclr = alloc(NN2);          // MCL result (persists across layers)
  float* mbuf = alloc(NN2);          // adj / m; later q|k then f1
  float* rt = alloc(NN2);            // MCL temp; later v|attn-out
  float* hbuf = alloc((size_t)BN * 128);  // h; later merge-out
  float* aggb = alloc((size_t)BN * 128);  // agg; later f2
  float* xbuf = alloc((size_t)BN * 128);  // post-attn LN output (FFN residual)
  float* deg = alloc(BN);
  float* dis = alloc(BN);

  float* qb = mbuf;
  float* kb = mbuf + (size_t)BN * 128;
  float* vb = rt;
  float* ob = rt + (size_t)BN * 128;
  float* om = hbuf;
  float* f1 = mbuf;
  float* f2 = aggb;
  float* outb = (float*)d_out;

  // ---- adjacency, degree, MCL ----
  hipMemsetAsync(mbuf, 0, NN2 * sizeof(float), stream);
  hipMemsetAsync(deg, 0, BN * sizeof(float), stream);
  build_adj_kernel<<<(E + 255) / 256, 256, 0, stream>>>(edge_index, mbuf, deg, E);
  selfloop_deg_kernel<<<BN / 256, 256, 0, stream>>>(n_counts, mbuf, deg, dis);
  norm_rows_kernel<<<BN, 256, 0, stream>>>(mbuf, mbuf, 0);
  dim3 mmg(4, 4, B);
  mcl_mm_kernel<<<mmg, 256, 0, stream>>>(mbuf, mbuf, rt);
  norm_rows_kernel<<<BN, 256, 0, stream>>>(rt, mclr, 0);
  for (int it = 1; it < 6; it++) {
    mcl_mm_kernel<<<mmg, 256, 0, stream>>>(mbuf, mclr, rt);
    norm_rows_kernel<<<BN, 256, 0, stream>>>(rt, mclr, (it == 2 || it == 5) ? 1 : 0);
  }

  // ---- running activation lives in d_out ----
  hipMemcpyAsync(outb, input_x, (size_t)BN * 128 * sizeof(float),
                 hipMemcpyDeviceToDevice, stream);

  dim3 g64x2(BN / 64, 2), g64x4(BN / 64, 4);
  for (int l = 0; l < NLAYER; l++) {
    // GCN
    gemm_nt_kernel<0><<<g64x2, 256, 0, stream>>>(outb, gcn_lin_w + (size_t)l * 128 * 128,
                                                 nullptr, hbuf, 128, 128, 1.0f);
    hipMemsetAsync(aggb, 0, (size_t)BN * 128 * sizeof(float), stream);
    edge_msg_kernel<<<(E * 128 + 255) / 256, 256, 0, stream>>>(
        edge_index, edge_attr, gcn_edge_w + (size_t)l * 128 * 7, hbuf, dis, aggb, E);
    gcn_post_kernel<<<BN / 4, 256, 0, stream>>>(aggb, hbuf, gcn_root + (size_t)l * 2 * 128,
                                                root, deg, gcn_ng + l * 128, gcn_nb + l * 128,
                                                outb);
    // attention
    gemm_nt_kernel<0><<<g64x2, 256, 0, stream>>>(outb, q_w + (size_t)l * 128 * 128, nullptr,
                                                 qb, 128, 128, 0.25f);
    gemm_nt_kernel<0><<<g64x2, 256, 0, stream>>>(outb, k_w + (size_t)l * 128 * 128, nullptr,
                                                 kb, 128, 128, 1.0f);
    gemm_nt_kernel<0><<<g64x2, 256, 0, stream>>>(outb, v_w + (size_t)l * 128 * 128, nullptr,
                                                 vb, 128, 128, 1.0f);
    dim3 ag(4, NHEAD, B);
    attn_kernel<<<ag, 64, 0, stream>>>(qb, kb, vb, mclr, mcl_w + l * NHEAD, n_counts, ob);
    gemm_nt_kernel<1><<<g64x2, 256, 0, stream>>>(ob, merge_w + (size_t)l * 128 * 128,
                                                 merge_b + l * 128, om, 128, 128, 1.0f);
    ln_add_kernel<<<BN / 4, 256, 0, stream>>>(om, outb, ln_in_g + l * 128, ln_in_b + l * 128,
                                              xbuf);
    // FFN
    gemm_nt_kernel<2><<<g64x4, 256, 0, stream>>>(xbuf, ffn_w1 + (size_t)l * 256 * 128,
                                                 ffn_b1 + l * 256, f1, 128, 256, 1.0f);
    gemm_nt_kernel<1><<<g64x2, 256, 0, stream>>>(f1, ffn_w2 + (size_t)l * 128 * 256,
                                                 ffn_b2 + l * 128, f2, 256, 128, 1.0f);
    ln_add_kernel<<<BN / 4, 256, 0, stream>>>(f2, xbuf, ln_ffn_g + l * 128,
                                              ln_ffn_b + l * 128, outb);
  }
  // final layernorm (in place on d_out)
  ln_add_kernel<<<BN / 4, 256, 0, stream>>>(outb, nullptr, final_g, final_b, outb);
}

// Round 2
// 1245.416 us; speedup vs baseline: 1.3568x; 1.3568x over previous
//
#include <hip/hip_runtime.h>
#include <hip/hip_bf16.h>
#include <math.h>

#define NFEAT 128
#define NNODE 256
#define NHEAD 8
#define DHEAD 16
#define NLAYER 9

// ---------------------------------------------------------------------------
// adjacency build: adj[b][s][t]=1 per edge; deg[row]+=1; ccount[col]+=1
__global__ void build_adj_kernel(const int* __restrict__ ei, float* __restrict__ adj,
                                 float* __restrict__ deg, int* __restrict__ ccount, int E) {
  int e = blockIdx.x * 256 + threadIdx.x;
  if (e >= E) return;
  int r = ei[e], c = ei[E + e];
  int b = r >> 8;
  adj[((size_t)b << 16) + ((size_t)(r & 255) << 8) + (c & 255)] = 1.0f;
  atomicAdd(&deg[r], 1.0f);
  atomicAdd(&ccount[c], 1);
}

// self loops on valid nodes; deg += 1; dis = deg^-1/2
__global__ void selfloop_deg_kernel(const int* __restrict__ nc, float* __restrict__ adj,
                                    float* __restrict__ deg, float* __restrict__ dis) {
  int n = blockIdx.x * 256 + threadIdx.x;
  int b = n >> 8, i = n & 255;
  if (i < nc[b]) adj[((size_t)b << 16) + ((size_t)i << 8) + i] = 1.0f;
  float d = deg[n] + 1.0f;
  deg[n] = d;
  dis[n] = rsqrtf(d);
}

// exclusive scan of ccount[4096] -> rowptr[4097]; one block of 1024 threads
__global__ __launch_bounds__(1024) void scan_kernel(const int* __restrict__ ccount,
                                                    int* __restrict__ rowptr, int n) {
  __shared__ int part[1024];
  int t = threadIdx.x;
  int base = t * 4;
  int c[4], s = 0;
#pragma unroll
  for (int i = 0; i < 4; i++) { c[i] = (base + i < n) ? ccount[base + i] : 0; s += c[i]; }
  part[t] = s;
  __syncthreads();
  for (int o = 1; o < 1024; o <<= 1) {
    int v = (t >= o) ? part[t - o] : 0;
    __syncthreads();
    part[t] += v;
    __syncthreads();
  }
  int excl = part[t] - s;
#pragma unroll
  for (int i = 0; i < 4; i++) {
    if (base + i < n) rowptr[base + i] = excl;
    excl += c[i];
  }
  if (t == 1023) rowptr[n] = part[1023];
}

// scatter edges into CSR order by target node; also precompute enorm
__global__ void scatter_kernel(const int* __restrict__ ei, const float* __restrict__ dis,
                               const int* __restrict__ rowptr, int* __restrict__ fill,
                               int* __restrict__ src_s, int* __restrict__ eidx_s,
                               float* __restrict__ enorm_s, int E) {
  int e = blockIdx.x * 256 + threadIdx.x;
  if (e >= E) return;
  int r = ei[e], c = ei[E + e];
  int pos = rowptr[c] + atomicAdd(&fill[c], 1);
  src_s[pos] = r;
  eidx_s[pos] = e;
  enorm_s[pos] = dis[r] * dis[c];
}

// row-normalize (optionally r^6 inflation first): one block (256 thr) per row
__global__ __launch_bounds__(256) void norm_rows_kernel(const float* __restrict__ src,
                                                        float* __restrict__ dst, int inflate) {
  int row = blockIdx.x;
  int t = threadIdx.x;
  float v = src[(size_t)row * 256 + t];
  if (inflate) { float v2 = v * v; v = v2 * v2 * v2; }
  float s = v;
#pragma unroll
  for (int o = 32; o > 0; o >>= 1) s += __shfl_xor(s, o, 64);
  __shared__ float ws4[4];
  if ((t & 63) == 0) ws4[t >> 6] = s;
  __syncthreads();
  float tot = ws4[0] + ws4[1] + ws4[2] + ws4[3];
  dst[(size_t)row * 256 + t] = v / (tot + 1e-6f);
}

// batched 256x256x256 NN matmul: C[b] = M[b] @ R[b]; grid (4,4,B), 64x64 tile
__global__ __launch_bounds__(256) void mcl_mm_kernel(const float* __restrict__ Mg,
                                                     const float* __restrict__ Rg,
                                                     float* __restrict__ Cg) {
  int b = blockIdx.z;
  const float* M = Mg + ((size_t)b << 16);
  const float* R = Rg + ((size_t)b << 16);
  float* C = Cg + ((size_t)b << 16);
  int i0 = blockIdx.x * 64, j0 = blockIdx.y * 64;
  int t = threadIdx.x;
  __shared__ float Ms[16][64], Rs[16][64];
  int lr = t >> 2, lc = (t & 3) * 4;
  int rr = t >> 4, rc = (t & 15) * 4;
  int ti = t >> 4, tj = t & 15;
  float acc[4][4] = {};
  for (int kc = 0; kc < 256; kc += 16) {
    float4 a4 = *(const float4*)(M + (size_t)(i0 + lr) * 256 + kc + lc);
    float4 r4 = *(const float4*)(R + (size_t)(kc + rr) * 256 + j0 + rc);
    Ms[lc + 0][lr] = a4.x; Ms[lc + 1][lr] = a4.y; Ms[lc + 2][lr] = a4.z; Ms[lc + 3][lr] = a4.w;
    *(float4*)&Rs[rr][rc] = r4;
    __syncthreads();
#pragma unroll
    for (int kk = 0; kk < 16; kk++) {
      float av[4], bv[4];
#pragma unroll
      for (int i = 0; i < 4; i++) { av[i] = Ms[kk][ti * 4 + i]; bv[i] = Rs[kk][tj * 4 + i]; }
#pragma unroll
      for (int i = 0; i < 4; i++)
#pragma unroll
        for (int j = 0; j < 4; j++) acc[i][j] += av[i] * bv[j];
    }
    __syncthreads();
  }
#pragma unroll
  for (int i = 0; i < 4; i++)
#pragma unroll
    for (int j = 0; j < 4; j++)
      C[(size_t)(i0 + ti * 4 + i) * 256 + j0 + tj * 4 + j] = acc[i][j];
}

__device__ inline float gelu_exact(float x) {
  return 0.5f * x * (1.0f + erff(x * 0.7071067811865476f));
}

// C[M,O] = act(A[M,K] @ W[O,K]^T); ACT 0: *scale, 1: +bias, 2: gelu(x+bias)
template <int ACT>
__global__ __launch_bounds__(256) void gemm_nt_kernel(const float* __restrict__ A,
                                                      const float* __restrict__ W,
                                                      const float* __restrict__ bias,
                                                      float* __restrict__ C, int K, int O,
                                                      float scale) {
  int m0 = blockIdx.x * 64, o0 = blockIdx.y * 64;
  int t = threadIdx.x;
  __shared__ float As[16][64], Ws[16][64];
  int lr = t >> 2, lc = (t & 3) * 4;
  int tm = t >> 4, to = t & 15;
  float acc[4][4] = {};
  for (int kc = 0; kc < K; kc += 16) {
    float4 a4 = *(const float4*)(A + (size_t)(m0 + lr) * K + kc + lc);
    float4 w4 = *(const float4*)(W + (size_t)(o0 + lr) * K + kc + lc);
    As[lc + 0][lr] = a4.x; As[lc + 1][lr] = a4.y; As[lc + 2][lr] = a4.z; As[lc + 3][lr] = a4.w;
    Ws[lc + 0][lr] = w4.x; Ws[lc + 1][lr] = w4.y; Ws[lc + 2][lr] = w4.z; Ws[lc + 3][lr] = w4.w;
    __syncthreads();
#pragma unroll
    for (int kk = 0; kk < 16; kk++) {
      float av[4], bv[4];
#pragma unroll
      for (int i = 0; i < 4; i++) { av[i] = As[kk][tm * 4 + i]; bv[i] = Ws[kk][to * 4 + i]; }
#pragma unroll
      for (int i = 0; i < 4; i++)
#pragma unroll
        for (int j = 0; j < 4; j++) acc[i][j] += av[i] * bv[j];
    }
    __syncthreads();
  }
#pragma unroll
  for (int i = 0; i < 4; i++) {
    int m = m0 + tm * 4 + i;
#pragma unroll
    for (int j = 0; j < 4; j++) {
      int oo = o0 + to * 4 + j;
      float v = acc[i][j];
      if (ACT == 0) v *= scale;
      else if (ACT == 1) v += bias[oo];
      else if (ACT == 2) v = gelu_exact(v + bias[oo]);
      C[(size_t)m * O + oo] = v;
    }
  }
}

// fused QKV projection: grid (BN/64, 6); y>>1 selects {q,k,v}, y&1 selects col half
__global__ __launch_bounds__(256) void gemm_qkv_kernel(const float* __restrict__ A,
                                                       const float* __restrict__ qw,
                                                       const float* __restrict__ kw,
                                                       const float* __restrict__ vw,
                                                       float* __restrict__ qkv, int BN) {
  int y = blockIdx.y;
  int which = y >> 1;
  const float* W = (which == 0) ? qw : (which == 1) ? kw : vw;
  float scale = (which == 0) ? 0.25f : 1.0f;
  float* C = qkv + (size_t)which * BN * 128;
  int m0 = blockIdx.x * 64, o0 = (y & 1) * 64;
  int t = threadIdx.x;
  __shared__ float As[16][64], Ws[16][64];
  int lr = t >> 2, lc = (t & 3) * 4;
  int tm = t >> 4, to = t & 15;
  float acc[4][4] = {};
  for (int kc = 0; kc < 128; kc += 16) {
    float4 a4 = *(const float4*)(A + (size_t)(m0 + lr) * 128 + kc + lc);
    float4 w4 = *(const float4*)(W + (size_t)(o0 + lr) * 128 + kc + lc);
    As[lc + 0][lr] = a4.x; As[lc + 1][lr] = a4.y; As[lc + 2][lr] = a4.z; As[lc + 3][lr] = a4.w;
    Ws[lc + 0][lr] = w4.x; Ws[lc + 1][lr] = w4.y; Ws[lc + 2][lr] = w4.z; Ws[lc + 3][lr] = w4.w;
    __syncthreads();
#pragma unroll
    for (int kk = 0; kk < 16; kk++) {
      float av[4], bv[4];
#pragma unroll
      for (int i = 0; i < 4; i++) { av[i] = As[kk][tm * 4 + i]; bv[i] = Ws[kk][to * 4 + i]; }
#pragma unroll
      for (int i = 0; i < 4; i++)
#pragma unroll
        for (int j = 0; j < 4; j++) acc[i][j] += av[i] * bv[j];
    }
    __syncthreads();
  }
#pragma unroll
  for (int i = 0; i < 4; i++) {
    int m = m0 + tm * 4 + i;
#pragma unroll
    for (int j = 0; j < 4; j++) C[(size_t)m * 128 + o0 + to * 4 + j] = acc[i][j] * scale;
  }
}

// fused GCN aggregate + post: one wave per node (2 feats/lane), CSR edge loop, no atomics.
// out += relu(LN(agg + relu(h + root_emb)/deg))
__global__ __launch_bounds__(256) void gcn_fused_kernel(
    const int* __restrict__ rowptr, const int* __restrict__ src_s,
    const int* __restrict__ eidx_s, const float* __restrict__ enorm_s,
    const float* __restrict__ ea, const float* __restrict__ We, const float* __restrict__ h,
    const float* __restrict__ remb, const int* __restrict__ root,
    const float* __restrict__ deg, const float* __restrict__ gamma,
    const float* __restrict__ beta, float* __restrict__ out) {
  __shared__ float Wt[7][128];  // transposed: Wt[k][f] = We[f*7+k]
  for (int idx = threadIdx.x; idx < 896; idx += 256) {
    int f = idx & 127, k = idx >> 7;
    Wt[k][f] = We[f * 7 + k];
  }
  __syncthreads();
  int n = blockIdx.x * 4 + (threadIdx.x >> 6);
  int lane = threadIdx.x & 63;
  int f0 = lane, f1 = lane + 64;
  int p0 = rowptr[n], p1 = rowptr[n + 1];
  float a0 = 0.f, a1 = 0.f;
  int r = 0, e = 0;
  float en = 0.f;
  if (p0 < p1) { r = src_s[p0]; e = eidx_s[p0]; en = enorm_s[p0]; }
  for (int p = p0; p < p1; p++) {
    int rn = 0, enx = 0;
    float ennx = 0.f;
    if (p + 1 < p1) { rn = src_s[p + 1]; enx = eidx_s[p + 1]; ennx = enorm_s[p + 1]; }
    const float* eae = ea + (size_t)e * 7;
    float h0 = h[(size_t)r * 128 + f0];
    float h1 = h[(size_t)r * 128 + f1];
    float d0 = 0.f, d1 = 0.f;
#pragma unroll
    for (int k = 0; k < 7; k++) {
      float ev = eae[k];
      d0 += ev * Wt[k][f0];
      d1 += ev * Wt[k][f1];
    }
    a0 += en * fmaxf(h0 + d0, 0.f);
    a1 += en * fmaxf(h1 + d1, 0.f);
    r = rn; e = enx; en = ennx;
  }
  float invd = 1.0f / deg[n];
  const float* re = remb + root[n] * 128;
  size_t base = (size_t)n * 128;
  float g0 = a0 + fmaxf(h[base + f0] + re[f0], 0.f) * invd;
  float g1 = a1 + fmaxf(h[base + f1] + re[f1], 0.f) * invd;
  float s = g0 + g1, ss = g0 * g0 + g1 * g1;
#pragma unroll
  for (int o = 32; o > 0; o >>= 1) { s += __shfl_xor(s, o, 64); ss += __shfl_xor(ss, o, 64); }
  float mu = s * 0.0078125f;
  float var = ss * 0.0078125f - mu * mu;
  float rs = rsqrtf(var + 1e-5f);
  float y0 = fmaxf((g0 - mu) * rs * gamma[f0] + beta[f0], 0.f);
  float y1 = fmaxf((g1 - mu) * rs * gamma[f1] + beta[f1], 0.f);
  out[base + f0] = y0 + out[base + f0];
  out[base + f1] = y1 + out[base + f1];
}

// dst = LN(a (+ res)) * gamma + beta
__global__ __launch_bounds__(256) void ln_add_kernel(const float* __restrict__ a,
                                                     const float* __restrict__ res,
                                                     const float* __restrict__ gamma,
                                                     const float* __restrict__ beta,
                                                     float* __restrict__ dst) {
  int n = blockIdx.x * 4 + (threadIdx.x >> 6);
  int lane = threadIdx.x & 63;
  size_t base = (size_t)n * 128;
  int f0 = lane, f1 = lane + 64;
  float x0 = a[base + f0], x1 = a[base + f1];
  if (res) { x0 += res[base + f0]; x1 += res[base + f1]; }
  float s = x0 + x1, ss = x0 * x0 + x1 * x1;
#pragma unroll
  for (int o = 32; o > 0; o >>= 1) { s += __shfl_xor(s, o, 64); ss += __shfl_xor(ss, o, 64); }
  float mu = s * 0.0078125f;
  float var = ss * 0.0078125f - mu * mu;
  float rs = rsqrtf(var + 1e-5f);
  dst[base + f0] = (x0 - mu) * rs * gamma[f0] + beta[f0];
  dst[base + f1] = (x1 - mu) * rs * gamma[f1] + beta[f1];
}

// biased MHA v2: 2 lanes per query (d split 8+8), fixed-max softmax.
// grid (2, H, B), block 256 (4 waves = 128 queries)
__global__ __launch_bounds__(256) void attn2_kernel(const float* __restrict__ q,
                                                    const float* __restrict__ k,
                                                    const float* __restrict__ v,
                                                    const float* __restrict__ mcl,
                                                    const float* __restrict__ mclw,
                                                    const int* __restrict__ ncnt,
                                                    float* __restrict__ o) {
  int qt = blockIdx.x, hh = blockIdx.y, b = blockIdx.z;
  int t = threadIdx.x;
  __shared__ float ks[256][16];
  __shared__ float vs[256][16];
  {
    const float* kp = k + ((size_t)(b * 256 + t) * 128 + hh * 16);
    const float* vp = v + ((size_t)(b * 256 + t) * 128 + hh * 16);
#pragma unroll
    for (int d4 = 0; d4 < 16; d4 += 4) {
      *(float4*)&ks[t][d4] = *(const float4*)(kp + d4);
      *(float4*)&vs[t][d4] = *(const float4*)(vp + d4);
    }
  }
  __syncthreads();
  int i = qt * 128 + (t >> 1);
  int d0 = (t & 1) * 8;
  int nc = ncnt[b];
  bool vi = i < nc;
  float wh = mclw[hh];
  float qv[8];
  const float* qp = q + ((size_t)(b * 256 + i) * 128 + hh * 16 + d0);
#pragma unroll
  for (int d = 0; d < 8; d++) qv[d] = qp[d];
  const float* mrow = mcl + ((size_t)(b * 256 + i)) * 256;
  float acc[8];
#pragma unroll
  for (int d = 0; d < 8; d++) acc[d] = 0.f;
  float lsum = 0.f;
  for (int j0 = 0; j0 < 256; j0 += 4) {
    float4 mc = *(const float4*)(mrow + j0);
    float mcv[4] = {mc.x, mc.y, mc.z, mc.w};
#pragma unroll
    for (int jj = 0; jj < 4; jj++) {
      int j = j0 + jj;
      float s = 0.f;
#pragma unroll
      for (int d = 0; d < 8; d++) s += qv[d] * ks[j][d0 + d];
      s += __shfl_xor(s, 1, 64);
      // fixed-max softmax: shift by -1024 for fully-padded query rows (matches ref softmax)
      float effb = vi ? (j < nc ? 0.f : -1024.f) : 0.f;
      float p = __expf(s + mcv[jj] * wh + effb);
      lsum += p;
#pragma unroll
      for (int d = 0; d < 8; d++) acc[d] += p * vs[j][d0 + d];
    }
  }
  float inv = 1.f / lsum;
  float* op = o + ((size_t)(b * 256 + i) * 128 + hh * 16 + d0);
  float4 o1 = {acc[0] * inv, acc[1] * inv, acc[2] * inv, acc[3] * inv};
  float4 o2 = {acc[4] * inv, acc[5] * inv, acc[6] * inv, acc[7] * inv};
  *(float4*)op = o1;
  *(float4*)(op + 4) = o2;
}

// ---------------------------------------------------------------------------
extern "C" void kernel_launch(void* const* d_in, const int* in_sizes, int n_in,
                              void* d_out, int out_size, void* d_ws, size_t ws_size,
                              hipStream_t stream) {
  const float* input_x = (const float*)d_in[0];
  const float* edge_attr = (const float*)d_in[1];
  const float* gcn_lin_w = (const float*)d_in[2];
  const float* gcn_root = (const float*)d_in[3];
  const float* gcn_edge_w = (const float*)d_in[4];
  const float* gcn_ng = (const float*)d_in[5];
  const float* gcn_nb = (const float*)d_in[6];
  const float* ln_in_g = (const float*)d_in[7];
  const float* ln_in_b = (const float*)d_in[8];
  const float* ln_ffn_g = (const float*)d_in[9];
  const float* ln_ffn_b = (const float*)d_in[10];
  const float* mcl_w = (const float*)d_in[11];
  const float* q_w = (const float*)d_in[12];
  const float* k_w = (const float*)d_in[13];
  const float* v_w = (const float*)d_in[14];
  const float* merge_w = (const float*)d_in[15];
  const float* merge_b = (const float*)d_in[16];
  const float* ffn_w1 = (const float*)d_in[17];
  const float* ffn_b1 = (const float*)d_in[18];
  const float* ffn_w2 = (const float*)d_in[19];
  const float* ffn_b2 = (const float*)d_in[20];
  const float* final_g = (const float*)d_in[21];
  const float* final_b = (const float*)d_in[22];
  const int* edge_index = (const int*)d_in[23];
  const int* n_counts = (const int*)d_in[24];
  const int* root = (const int*)d_in[25];

  const int E = in_sizes[23] / 2;
  const int B = in_sizes[24];
  const int BN = B * NNODE;

  float* ws = (float*)d_ws;
  size_t off = 0;
  auto alloc = [&](size_t n) { float* p = ws + off; off += n; return p; };
  const size_t NN2 = (size_t)B * 256 * 256;
  const size_t XF = (size_t)BN * 128;
  float* mclr = alloc(NN2);   // MCL bias (persists across layers)
  float* mbuf = alloc(NN2);   // adj/m; later qkv (spans into rt)
  float* rt = alloc(NN2);     // MCL temp; later qkv tail + ob, then f1
  float* hbuf = alloc(XF);    // h; later f2
  float* xbuf = alloc(XF);    // post-attn LN output (FFN residual)
  float* deg = alloc(BN);
  float* dis = alloc(BN);
  int* rowptr = (int*)alloc(BN + 1);
  int* ccount = (int*)alloc(BN);
  int* fill = (int*)alloc(BN);
  int* src_s = (int*)alloc(E);
  int* eidx_s = (int*)alloc(E);
  float* enorm_s = alloc(E);

  // layer-temp aliasing (mbuf+rt = 2*NN2 contiguous floats)
  float* qkv = mbuf;          // 3*XF <= 2*NN2
  float* ob = mbuf + 3 * XF;  // attn output
  float* om = mbuf;           // merge output (q/k/v dead)
  float* f1 = rt;             // FFN hidden (ob dead by then); BN*256 = NN2
  float* f2 = hbuf;           // h dead after gcn_fused
  float* outb = (float*)d_out;

  // ---- one-time: adjacency, degree, CSR, MCL ----
  hipMemsetAsync(mbuf, 0, NN2 * sizeof(float), stream);
  hipMemsetAsync(deg, 0, BN * sizeof(float), stream);
  hipMemsetAsync(ccount, 0, BN * sizeof(int), stream);
  hipMemsetAsync(fill, 0, BN * sizeof(int), stream);
  build_adj_kernel<<<(E + 255) / 256, 256, 0, stream>>>(edge_index, mbuf, deg, ccount, E);
  selfloop_deg_kernel<<<BN / 256, 256, 0, stream>>>(n_counts, mbuf, deg, dis);
  scan_kernel<<<1, 1024, 0, stream>>>(ccount, rowptr, BN);
  scatter_kernel<<<(E + 255) / 256, 256, 0, stream>>>(edge_index, dis, rowptr, fill, src_s,
                                                      eidx_s, enorm_s, E);
  norm_rows_kernel<<<BN, 256, 0, stream>>>(mbuf, mbuf, 0);
  dim3 mmg(4, 4, B);
  mcl_mm_kernel<<<mmg, 256, 0, stream>>>(mbuf, mbuf, rt);
  norm_rows_kernel<<<BN, 256, 0, stream>>>(rt, mclr, 0);
  for (int it = 1; it < 6; it++) {
    mcl_mm_kernel<<<mmg, 256, 0, stream>>>(mbuf, mclr, rt);
    norm_rows_kernel<<<BN, 256, 0, stream>>>(rt, mclr, (it == 2 || it == 5) ? 1 : 0);
  }

  // ---- running activation lives in d_out ----
  hipMemcpyAsync(outb, input_x, XF * sizeof(float), hipMemcpyDeviceToDevice, stream);

  dim3 g64x2(BN / 64, 2), g64x4(BN / 64, 4), g64x6(BN / 64, 6);
  dim3 ag(2, NHEAD, B);
  for (int l = 0; l < NLAYER; l++) {
    // GCN
    gemm_nt_kernel<0><<<g64x2, 256, 0, stream>>>(outb, gcn_lin_w + (size_t)l * 128 * 128,
                                                 nullptr, hbuf, 128, 128, 1.0f);
    gcn_fused_kernel<<<BN / 4, 256, 0, stream>>>(
        rowptr, src_s, eidx_s, enorm_s, edge_attr, gcn_edge_w + (size_t)l * 128 * 7, hbuf,
        gcn_root + (size_t)l * 2 * 128, root, deg, gcn_ng + l * 128, gcn_nb + l * 128, outb);
    // attention
    gemm_qkv_kernel<<<g64x6, 256, 0, stream>>>(outb, q_w + (size_t)l * 128 * 128,
                                               k_w + (size_t)l * 128 * 128,
                                               v_w + (size_t)l * 128 * 128, qkv, BN);
    attn2_kernel<<<ag, 256, 0, stream>>>(qkv, qkv + XF, qkv + 2 * XF, mclr,
                                         mcl_w + l * NHEAD, n_counts, ob);
    gemm_nt_kernel<1><<<g64x2, 256, 0, stream>>>(ob, merge_w + (size_t)l * 128 * 128,
                                                 merge_b + l * 128, om, 128, 128, 1.0f);
    ln_add_kernel<<<BN / 4, 256, 0, stream>>>(om, outb, ln_in_g + l * 128, ln_in_b + l * 128,
                                              xbuf);
    // FFN
    gemm_nt_kernel<2><<<g64x4, 256, 0, stream>>>(xbuf, ffn_w1 + (size_t)l * 256 * 128,
                                                 ffn_b1 + l * 256, f1, 128, 256, 1.0f);
    gemm_nt_kernel<1><<<g64x2, 256, 0, stream>>>(f1, ffn_w2 + (size_t)l * 128 * 256,
                                                 ffn_b2 + l * 128, f2, 256, 128, 1.0f);
    ln_add_kernel<<<BN / 4, 256, 0, stream>>>(f2, xbuf, ln_ffn_g + l * 128,
                                              ln_ffn_b + l * 128, outb);
  }
  // final layernorm (in place on d_out)
  ln_add_kernel<<<BN / 4, 256, 0, stream>>>(outb, nullptr, final_g, final_b, outb);
}